// Round 1
// baseline (88.104 us; speedup 1.0000x reference)
//
#include <hip/hip_runtime.h>

// SourcePE: out[n,b,e] = dropout( emb[n,b,e] + sin(box[b,n,e&3] * den[e>>2]) )
// dropout mask = JAX threefry2x32, key(42)=(0,42), partitionable path:
//   bits(i) = out0 ^ out1 of threefry((0,42), (0, i));  keep = (bits>>9) < 7549747
// (0.9f == 7549747 * 2^-23 exactly, so the integer compare is bit-exact vs
//  uniform(key) < 0.9f)

namespace {

constexpr int      NBOX    = 1024;
constexpr int      BATCH_  = 64;
constexpr int      EMB_    = 512;
constexpr unsigned TOTAL_G = (unsigned)NBOX * BATCH_ * (EMB_ / 4);  // 8388608 float4-groups

// threefry2x32, key = (0, 42): ks0=0, ks1=42, ks2=0^42^0x1BD11BDA=0x1BD11BF0
// counter = (0, ctr). Returns x0 ^ x1 (the partitionable 32-bit combine).
__device__ __forceinline__ unsigned threefry_xor(unsigned ctr) {
  unsigned x0 = 0u;          // counts_hi + ks0
  unsigned x1 = ctr + 42u;   // counts_lo + ks1
#define TFR(r) { x0 += x1; x1 = ((x1 << (r)) | (x1 >> (32 - (r)))) ^ x0; }
  TFR(13) TFR(15) TFR(26) TFR(6)
  x0 += 42u;          x1 += 0x1BD11BF1u;   // ks1, ks2+1
  TFR(17) TFR(29) TFR(16) TFR(24)
  x0 += 0x1BD11BF0u;  x1 += 2u;            // ks2, ks0+2
  TFR(13) TFR(15) TFR(26) TFR(6)
  /* x0 += ks0 (=0) */ x1 += 45u;          // ks1+3
  TFR(17) TFR(29) TFR(16) TFR(24)
  x0 += 42u;          x1 += 0x1BD11BF4u;   // ks1, ks2+4
  TFR(13) TFR(15) TFR(26) TFR(6)
  x0 += 0x1BD11BF0u;  x1 += 5u;            // ks2, ks0+5
#undef TFR
  return x0 ^ x1;
}

__global__ __launch_bounds__(256) void pe_add_dropout(
    const float4* __restrict__ emb,
    const int4*   __restrict__ boxes,
    float4*       __restrict__ out) {
  // den[j] = exp(-j*ln(10000)/2048) = exp2(-j * log2(10000)/2048)
  const float K2 = 0.0064881408103268795f;  // log2(10000)/2048
  const float SC = 1.11111111111111111f;    // 1/0.9
  const unsigned stride = gridDim.x * blockDim.x;
  for (unsigned g = blockIdx.x * blockDim.x + threadIdx.x; g < TOTAL_G; g += stride) {
    const unsigned j   = g & 127u;   // EMB/4 = 128 groups per (n,b) row
    const unsigned row = g >> 7;     // n*64 + b
    const unsigned b   = row & 63u;
    const unsigned n   = row >> 6;

    const float4 e  = emb[g];
    const int4   bx = boxes[b * NBOX + n];

    const float den = exp2f(-(float)j * K2);
    const float s0 = __sinf((float)bx.x * den);
    const float s1 = __sinf((float)bx.y * den);
    const float s2 = __sinf((float)bx.z * den);
    const float s3 = __sinf((float)bx.w * den);

    const unsigned i0 = g << 2;  // flat element index of lane .x
    const unsigned m0 = threefry_xor(i0);
    const unsigned m1 = threefry_xor(i0 + 1u);
    const unsigned m2 = threefry_xor(i0 + 2u);
    const unsigned m3 = threefry_xor(i0 + 3u);

    float4 r;
    r.x = ((m0 >> 9) < 7549747u) ? (e.x + s0) * SC : 0.0f;
    r.y = ((m1 >> 9) < 7549747u) ? (e.y + s1) * SC : 0.0f;
    r.z = ((m2 >> 9) < 7549747u) ? (e.z + s2) * SC : 0.0f;
    r.w = ((m3 >> 9) < 7549747u) ? (e.w + s3) * SC : 0.0f;
    out[g] = r;
  }
}

}  // namespace

extern "C" void kernel_launch(void* const* d_in, const int* in_sizes, int n_in,
                              void* d_out, int out_size, void* d_ws, size_t ws_size,
                              hipStream_t stream) {
  const float4* emb   = (const float4*)d_in[0];  // (1024, 64, 512) f32
  const int4*   boxes = (const int4*)d_in[1];    // (64, 1024, 4) i32
  float4*       outp  = (float4*)d_out;          // (1024, 64, 512) f32
  dim3 grid(2048), block(256);
  hipLaunchKernelGGL(pe_add_dropout, grid, block, 0, stream, emb, boxes, outp);
}

// Round 2
// 78.526 us; speedup vs baseline: 1.1220x; 1.1220x over previous
//
#include <hip/hip_runtime.h>

// SourcePE: out[n,b,e] = dropout( emb[n,b,e] + sin(box[b,n,e&3] * den[e>>2]) )
// dropout mask = JAX threefry2x32, key(42)=(0,42), partitionable path:
//   bits(i) = out0 ^ out1 of threefry((0,42), (0, i))
//   keep <=> (bits>>9) < 7549747  <=>  bits < 7549747*512 = 3865470464
// (verified bit-exact in R1: absmax 0.031 = sin approx only)

namespace {

constexpr int      NBOX     = 1024;
constexpr unsigned TOTAL_G  = 1024u * 64u * 128u;  // 8388608 float4-groups
constexpr unsigned NBLK     = 2048;
constexpr unsigned NTHR     = 256;
constexpr unsigned STRIDE_G = NBLK * NTHR;         // 524288 groups per sweep
constexpr int      ITERS    = TOTAL_G / STRIDE_G;  // 16
// stride = 4096 rows => per-thread: j invariant, b invariant, n += 64 per iter

__device__ __forceinline__ unsigned rotl(unsigned x, int r) {
  // v_alignbit_b32 x:x >> (32-r) == rotl(x, r) — force single-instr rotate
  return __builtin_amdgcn_alignbit(x, x, 32 - r);
}

// threefry2x32, key=(0,42): ks0=0, ks1=42, ks2=0x1BD11BDA^42=0x1BD11BF0
__device__ __forceinline__ unsigned threefry_xor(unsigned ctr) {
  unsigned x0 = 0u;          // ctr_hi + ks0
  unsigned x1 = ctr + 42u;   // ctr_lo + ks1
#define R4(a,b,c,d)                       \
  x0 += x1; x1 = rotl(x1,(a)) ^ x0;       \
  x0 += x1; x1 = rotl(x1,(b)) ^ x0;       \
  x0 += x1; x1 = rotl(x1,(c)) ^ x0;       \
  x0 += x1; x1 = rotl(x1,(d)) ^ x0;
  R4(13,15,26,6)
  x0 += 42u;          x1 += 0x1BD11BF1u;  // ks1, ks2+1
  R4(17,29,16,24)
  x0 += 0x1BD11BF0u;  x1 += 2u;           // ks2, ks0+2
  R4(13,15,26,6)
  /* ks0 = 0 */       x1 += 45u;          // ks1+3
  R4(17,29,16,24)
  x0 += 42u;          x1 += 0x1BD11BF4u;  // ks1, ks2+4
  R4(13,15,26,6)
  x0 += 0x1BD11BF0u;  x1 += 5u;           // ks2, ks0+5
#undef R4
  return x0 ^ x1;
}

__global__ __launch_bounds__(256) void pe_add_dropout(
    const float4* __restrict__ emb,
    const int4*   __restrict__ boxes,
    float4*       __restrict__ out) {
  const float K2 = 0.0064881408103268795f;  // log2(10000)/2048
  const float SC = 1.11111111111111111f;    // 1/0.9

  unsigned g = blockIdx.x * NTHR + threadIdx.x;   // < 524288
  const unsigned j    = g & 127u;
  const unsigned row0 = g >> 7;                   // < 4096
  const unsigned b    = row0 & 63u;
  const unsigned n0   = row0 >> 6;                // < 64

  const float den = exp2f(-(float)j * K2);        // hoisted: j invariant
  const int4* bp  = boxes + (b * NBOX + n0);      // n advances by +64/iter
  unsigned i0 = g << 2;                           // flat element index

#pragma unroll 2
  for (int it = 0; it < ITERS; ++it) {
    const float4 e  = emb[g];
    const int4   bx = *bp;

    const float s0 = __sinf((float)bx.x * den);
    const float s1 = __sinf((float)bx.y * den);
    const float s2 = __sinf((float)bx.z * den);
    const float s3 = __sinf((float)bx.w * den);

    const unsigned m0 = threefry_xor(i0);
    const unsigned m1 = threefry_xor(i0 + 1u);
    const unsigned m2 = threefry_xor(i0 + 2u);
    const unsigned m3 = threefry_xor(i0 + 3u);

    float4 r;
    r.x = (m0 < 3865470464u) ? (e.x + s0) * SC : 0.0f;
    r.y = (m1 < 3865470464u) ? (e.y + s1) * SC : 0.0f;
    r.z = (m2 < 3865470464u) ? (e.z + s2) * SC : 0.0f;
    r.w = (m3 < 3865470464u) ? (e.w + s3) * SC : 0.0f;
    out[g] = r;

    g  += STRIDE_G;
    bp += 64;                 // n += 64
    i0 += STRIDE_G * 4u;
  }
}

}  // namespace

extern "C" void kernel_launch(void* const* d_in, const int* in_sizes, int n_in,
                              void* d_out, int out_size, void* d_ws, size_t ws_size,
                              hipStream_t stream) {
  const float4* emb   = (const float4*)d_in[0];  // (1024, 64, 512) f32
  const int4*   boxes = (const int4*)d_in[1];    // (64, 1024, 4) i32
  float4*       outp  = (float4*)d_out;          // (1024, 64, 512) f32
  hipLaunchKernelGGL(pe_add_dropout, dim3(NBLK), dim3(NTHR), 0, stream,
                     emb, boxes, outp);
}